// Round 10
// baseline (272.128 us; speedup 1.0000x reference)
//
#include <hip/hip_runtime.h>
#include <hip/hip_fp16.h>
#include <math.h>

#define F_IN 128
#define HID 64
#define HID2 32
#define EPS_BN 1e-5f
#define BW 128          // nodes per bucket
#define NBMAX 1024      // padded bucket count (actual NB = 782)
#define CAP 2560        // max edges per bucket (mean ~2046, +11 sigma)
#define CH 8192         // edges per partition workgroup

// ---------------- phase A: chunk counting-sort into bucket regions (1024 thr) ----------------
__global__ __launch_bounds__(1024) void partition_kernel(const int* __restrict__ src, const int* __restrict__ dst,
                                                         int E, int* __restrict__ gcursor,
                                                         unsigned* __restrict__ ebuf) {
    __shared__ int hist[NBMAX];
    __shared__ int start[NBMAX];
    __shared__ int cur[NBMAX];
    __shared__ int gb[NBMAX];
    __shared__ int sc[1024];
    __shared__ unsigned buf[CH];  // 32 KB
    int tid = threadIdx.x;
    int e0 = blockIdx.x * CH;
    hist[tid] = 0;
    __syncthreads();
#pragma unroll
    for (int it = 0; it < CH / 1024; it++) {
        int e = e0 + tid + it * 1024;
        if (e < E) atomicAdd(&hist[dst[e] >> 7], 1);
    }
    __syncthreads();
    int v = hist[tid];
    sc[tid] = v;
    __syncthreads();
    for (int off = 1; off < 1024; off <<= 1) {
        int t = (tid >= off) ? sc[tid - off] : 0;
        __syncthreads();
        sc[tid] += t;
        __syncthreads();
    }
    int ex = sc[tid] - v;  // exclusive prefix over buckets
    start[tid] = ex;
    cur[tid] = ex;
    gb[tid] = v ? atomicAdd(&gcursor[tid], v) : 0;   // reserve run in bucket region
    __syncthreads();
#pragma unroll
    for (int it = 0; it < CH / 1024; it++) {
        int e = e0 + tid + it * 1024;
        if (e < E) {
            int d = dst[e], s = src[e];
            int p = atomicAdd(&cur[d >> 7], 1);
            buf[p] = ((unsigned)(d & (BW - 1)) << 17) | (unsigned)s;  // src < 2^17
        }
    }
    __syncthreads();
    // write phase: 256 quad-groups x 4 buckets each
    int grp = tid >> 2, sub = tid & 3;
    for (int b = grp; b < NBMAX; b += 256) {
        int len = hist[b];
        if (!len) continue;
        int st = start[b];
        unsigned* dp = ebuf + (size_t)b * CAP + gb[b];
        for (int i = sub; i < len; i += 4) dp[i] = buf[st + i];
    }
}

// ---------------- phase B: per-bucket local sort; emits ns/ne/dinv and csr (in-place) ----------------
__global__ __launch_bounds__(256) void localsort_kernel(unsigned* __restrict__ ebuf, const int* __restrict__ gcursor,
                                                        int* __restrict__ ns, int* __restrict__ ne,
                                                        float* __restrict__ dinv, int n) {
    __shared__ unsigned lbuf[CAP];
    __shared__ int lhist[BW];
    __shared__ int lcur[BW];
    __shared__ int stmp[256];
    int b = blockIdx.x;
    int tid = threadIdx.x;
    int base = b * CAP;
    int len = gcursor[b];
    int node0 = b * BW;
    int nn = min(BW, n - node0);
    if (tid < BW) lhist[tid] = 0;
    __syncthreads();
    for (int k = tid; k < len; k += 256) {
        unsigned u = ebuf[base + k];
        lbuf[k] = u;
        atomicAdd(&lhist[u >> 17], 1);
    }
    __syncthreads();
    int v = (tid < BW) ? lhist[tid] : 0;
    stmp[tid] = v;
    __syncthreads();
    for (int off = 1; off < 256; off <<= 1) {
        int t = (tid >= off) ? stmp[tid - off] : 0;
        __syncthreads();
        stmp[tid] += t;
        __syncthreads();
    }
    int ex = stmp[tid] - v;  // exclusive within bucket
    if (tid < BW) lcur[tid] = ex;
    if (tid < nn) {
        ns[node0 + tid] = base + ex;
        ne[node0 + tid] = base + ex + v;
        dinv[node0 + tid] = rsqrtf((float)(v + 1));   // +1 self-loop
    }
    __syncthreads();
    for (int k = tid; k < len; k += 256) {
        unsigned u = lbuf[k];
        int p = atomicAdd(&lcur[u >> 17], 1);
        ebuf[base + p] = u & 0x1FFFFu;               // store global src id
    }
}

// ---------------- fold BN(eval)+bias into per-column scale/shift ----------------
__global__ void constprep_kernel(const float* g1, const float* be1, const float* rm1, const float* rv1, const float* b1,
                                 const float* g2, const float* be2, const float* rm2, const float* rv2, const float* b2,
                                 float* A1, float* B1, float* A2, float* B2) {
    int t = threadIdx.x;
    if (t < HID)  { float s = g1[t] * rsqrtf(rv1[t] + EPS_BN); A1[t] = s; B1[t] = (b1[t] - rm1[t]) * s + be1[t]; }
    if (t < HID2) { float s = g2[t] * rsqrtf(rv2[t] + EPS_BN); A2[t] = s; B2[t] = (b2[t] - rm2[t]) * s + be2[t]; }
}

// ---------------- GEMM1: ht1 = fp16( (x @ W1) * dinv[row] ) ----------------
// W in LDS (32 KB only -> 5 blocks/CU); x streamed from global (16-lane broadcast + L1 reuse)
__global__ __launch_bounds__(256, 5) void gemm1_kernel(const float* __restrict__ x, const float* __restrict__ W1,
                                                       const float* __restrict__ dinv, __half* __restrict__ ht1,
                                                       int n) {
    __shared__ float wlds[F_IN * HID];   // 32 KB, [k][col]
    int tid = threadIdx.x;
    {
        const float4* wv = (const float4*)W1;
        float4* wl = (float4*)wlds;
#pragma unroll
        for (int i = 0; i < F_IN * HID / 4 / 256; i++) wl[tid + 256 * i] = wv[tid + 256 * i];
    }
    __syncthreads();
    int row0 = blockIdx.x * 64;
    int col4 = (tid & 15) * 4;
    int rowg = tid >> 4;                 // 0..15 -> rows rowg*4..+3
    // clamp row pointers for OOB rows (loads valid, stores guarded)
    const float* xr[4];
#pragma unroll
    for (int r = 0; r < 4; r++) {
        int rr = row0 + rowg * 4 + r;
        xr[r] = x + (size_t)min(rr, n - 1) * F_IN;
    }
    float acc[4][4];
#pragma unroll
    for (int r = 0; r < 4; r++)
#pragma unroll
        for (int c = 0; c < 4; c++) acc[r][c] = 0.f;
#pragma unroll 4
    for (int k = 0; k < F_IN; k += 4) {
        float4 xa[4];
#pragma unroll
        for (int r = 0; r < 4; r++) xa[r] = *(const float4*)(xr[r] + k);
        float4 wb[4];
#pragma unroll
        for (int j = 0; j < 4; j++) wb[j] = *(const float4*)&wlds[(k + j) * HID + col4];
#pragma unroll
        for (int r = 0; r < 4; r++) {
            acc[r][0] = fmaf(xa[r].x, wb[0].x, acc[r][0]); acc[r][1] = fmaf(xa[r].x, wb[0].y, acc[r][1]);
            acc[r][2] = fmaf(xa[r].x, wb[0].z, acc[r][2]); acc[r][3] = fmaf(xa[r].x, wb[0].w, acc[r][3]);
            acc[r][0] = fmaf(xa[r].y, wb[1].x, acc[r][0]); acc[r][1] = fmaf(xa[r].y, wb[1].y, acc[r][1]);
            acc[r][2] = fmaf(xa[r].y, wb[1].z, acc[r][2]); acc[r][3] = fmaf(xa[r].y, wb[1].w, acc[r][3]);
            acc[r][0] = fmaf(xa[r].z, wb[2].x, acc[r][0]); acc[r][1] = fmaf(xa[r].z, wb[2].y, acc[r][1]);
            acc[r][2] = fmaf(xa[r].z, wb[2].z, acc[r][2]); acc[r][3] = fmaf(xa[r].z, wb[2].w, acc[r][3]);
            acc[r][0] = fmaf(xa[r].w, wb[3].x, acc[r][0]); acc[r][1] = fmaf(xa[r].w, wb[3].y, acc[r][1]);
            acc[r][2] = fmaf(xa[r].w, wb[3].z, acc[r][2]); acc[r][3] = fmaf(xa[r].w, wb[3].w, acc[r][3]);
        }
    }
    int rbase = row0 + rowg * 4;
#pragma unroll
    for (int r = 0; r < 4; r++) {
        int row = rbase + r;
        if (row < n) {
            float d = dinv[row];
            __half2 h0, h1;
            h0.x = __float2half(acc[r][0] * d); h0.y = __float2half(acc[r][1] * d);
            h1.x = __float2half(acc[r][2] * d); h1.y = __float2half(acc[r][3] * d);
            __half2* dp = (__half2*)(ht1 + (size_t)row * HID + col4);
            dp[0] = h0; dp[1] = h1;
        }
    }
}

// ---------------- GEMM2: ht2 = fp16( (h1p @ W2) * dinv[row] ) ----------------
#define XP2 68
__global__ __launch_bounds__(256) void gemm2_kernel(const float* __restrict__ h1p, const float* __restrict__ W2,
                                                    const float* __restrict__ dinv, __half* __restrict__ ht2,
                                                    int n) {
    __shared__ float wlds[HID * HID2];   // 8 KB, [k][col]
    __shared__ float xlds[64 * XP2];     // 17.4 KB
    int tid = threadIdx.x;
    {
        const float4* wv = (const float4*)W2;
        float4* wl = (float4*)wlds;
#pragma unroll
        for (int i = 0; i < HID * HID2 / 4 / 256; i++) wl[tid + 256 * i] = wv[tid + 256 * i];
    }
    int row0 = blockIdx.x * 64;
    {
        const float4* xv = (const float4*)(h1p + (size_t)row0 * HID);
        int lim = (n - row0) * (HID / 4);
#pragma unroll
        for (int i = 0; i < 4; i++) {
            int f = tid + 256 * i;
            float4 v = make_float4(0.f, 0.f, 0.f, 0.f);
            if (f < lim) v = xv[f];
            int r = f >> 4, kp = (f & 15) * 4;
            *(float4*)&xlds[r * XP2 + kp] = v;
        }
    }
    __syncthreads();
    int col4 = (tid & 7) * 4;
    int rowg = tid >> 3;
    float acc[2][4];
#pragma unroll
    for (int r = 0; r < 2; r++)
#pragma unroll
        for (int c = 0; c < 4; c++) acc[r][c] = 0.f;
#pragma unroll 4
    for (int k = 0; k < HID; k += 4) {
        float4 wb[4];
#pragma unroll
        for (int j = 0; j < 4; j++) wb[j] = *(const float4*)&wlds[(k + j) * HID2 + col4];
#pragma unroll
        for (int r = 0; r < 2; r++) {
            float4 xa = *(const float4*)&xlds[(rowg * 2 + r) * XP2 + k];
            acc[r][0] = fmaf(xa.x, wb[0].x, acc[r][0]); acc[r][1] = fmaf(xa.x, wb[0].y, acc[r][1]);
            acc[r][2] = fmaf(xa.x, wb[0].z, acc[r][2]); acc[r][3] = fmaf(xa.x, wb[0].w, acc[r][3]);
            acc[r][0] = fmaf(xa.y, wb[1].x, acc[r][0]); acc[r][1] = fmaf(xa.y, wb[1].y, acc[r][1]);
            acc[r][2] = fmaf(xa.y, wb[1].z, acc[r][2]); acc[r][3] = fmaf(xa.y, wb[1].w, acc[r][3]);
            acc[r][0] = fmaf(xa.z, wb[2].x, acc[r][0]); acc[r][1] = fmaf(xa.z, wb[2].y, acc[r][1]);
            acc[r][2] = fmaf(xa.z, wb[2].z, acc[r][2]); acc[r][3] = fmaf(xa.z, wb[2].w, acc[r][3]);
            acc[r][0] = fmaf(xa.w, wb[3].x, acc[r][0]); acc[r][1] = fmaf(xa.w, wb[3].y, acc[r][1]);
            acc[r][2] = fmaf(xa.w, wb[3].z, acc[r][2]); acc[r][3] = fmaf(xa.w, wb[3].w, acc[r][3]);
        }
    }
    int rbase = row0 + rowg * 2;
#pragma unroll
    for (int r = 0; r < 2; r++) {
        int row = rbase + r;
        if (row < n) {
            float d = dinv[row];
            __half2 h0, h1;
            h0.x = __float2half(acc[r][0] * d); h0.y = __float2half(acc[r][1] * d);
            h1.x = __float2half(acc[r][2] * d); h1.y = __float2half(acc[r][3] * d);
            __half2* dp = (__half2*)(ht2 + (size_t)row * HID2 + col4);
            dp[0] = h0; dp[1] = h1;
        }
    }
}

// ---------------- agg1: node-parallel, predicated 16-edge blocks (no serial remainder) ----------------
// wave = 1 node; eh = lane>>5 edge-parity, cp = lane&31 half2-column
__global__ __launch_bounds__(256) void agg1_kernel(const __half* __restrict__ ht1, const int* __restrict__ ns,
                                                   const int* __restrict__ ne, const int* __restrict__ csr,
                                                   const float* __restrict__ dinv,
                                                   const float* __restrict__ A1, const float* __restrict__ B1,
                                                   float* __restrict__ h1p, int n) {
    int node = (blockIdx.x * blockDim.x + threadIdx.x) >> 6;
    if (node >= n) return;
    int lane = threadIdx.x & 63;
    int eh = lane >> 5, cp = lane & 31;
    const __half2* htp = (const __half2*)ht1;   // [n][32] half2
    int s = ns[node], e_end = ne[node];
    float ax = 0.f, ay = 0.f;
    if (eh == 0) {  // self-loop term counted once
        float2 f = __half22float2(htp[(size_t)node * 32 + cp]);
        ax = f.x; ay = f.y;
    }
    // fully predicated: ceil(d/16) blocks of 16 slots; invalid slots clamp to csr[s]
    for (int i = s + eh; i < e_end; i += 16) {
        int idx[8];
        bool val[8];
#pragma unroll
        for (int j = 0; j < 8; j++) {
            int e = i + 2 * j;
            val[j] = e < e_end;
            idx[j] = csr[val[j] ? e : s];
        }
#pragma unroll
        for (int j = 0; j < 8; j++) {
            float2 f = __half22float2(htp[(size_t)idx[j] * 32 + cp]);
            ax += val[j] ? f.x : 0.f;
            ay += val[j] ? f.y : 0.f;
        }
    }
    ax += __shfl_xor(ax, 32);
    ay += __shfl_xor(ay, 32);
    if (eh == 0) {
        float d = dinv[node];
        int c0 = cp * 2;
        float2 o;
        o.x = fmaxf(fmaf(ax * d, A1[c0], B1[c0]), 0.f);
        o.y = fmaxf(fmaf(ay * d, A1[c0 + 1], B1[c0 + 1]), 0.f);
        *(float2*)&h1p[(size_t)node * HID + c0] = o;
    }
}

// ---------------- agg2: node-parallel, predicated 16-edge blocks + classifier + log_softmax ----------------
// eq = lane>>4 edge-quad, cp = lane&15 half2-column
__global__ __launch_bounds__(256) void agg2_kernel(const __half* __restrict__ ht2, const int* __restrict__ ns,
                                                   const int* __restrict__ ne, const int* __restrict__ csr,
                                                   const float* __restrict__ dinv,
                                                   const float* __restrict__ A2, const float* __restrict__ B2,
                                                   const float* __restrict__ Wc, const float* __restrict__ bc,
                                                   float* __restrict__ out, int n) {
    int node = (blockIdx.x * blockDim.x + threadIdx.x) >> 6;
    if (node >= n) return;
    int lane = threadIdx.x & 63;
    int eq = lane >> 4, cp = lane & 15;
    const __half2* htp = (const __half2*)ht2;   // [n][16] half2
    int s = ns[node], e_end = ne[node];
    float ax = 0.f, ay = 0.f;
    if (eq == 0) {
        float2 f = __half22float2(htp[(size_t)node * 16 + cp]);
        ax = f.x; ay = f.y;
    }
    for (int i = s + eq; i < e_end; i += 16) {
        int idx[4];
        bool val[4];
#pragma unroll
        for (int j = 0; j < 4; j++) {
            int e = i + 4 * j;
            val[j] = e < e_end;
            idx[j] = csr[val[j] ? e : s];
        }
#pragma unroll
        for (int j = 0; j < 4; j++) {
            float2 f = __half22float2(htp[(size_t)idx[j] * 16 + cp]);
            ax += val[j] ? f.x : 0.f;
            ay += val[j] ? f.y : 0.f;
        }
    }
    ax += __shfl_xor(ax, 32); ay += __shfl_xor(ay, 32);
    ax += __shfl_xor(ax, 16); ay += __shfl_xor(ay, 16);
    // all lanes hold full sums for cols 2cp, 2cp+1
    float d = dinv[node];
    int c0 = cp * 2;
    float v0 = fmaxf(fmaf(ax * d, A2[c0], B2[c0]), 0.f);
    float v1 = fmaxf(fmaf(ay * d, A2[c0 + 1], B2[c0 + 1]), 0.f);
    float p0 = v0 * Wc[c0 * 2 + 0] + v1 * Wc[c0 * 2 + 2];
    float p1 = v0 * Wc[c0 * 2 + 1] + v1 * Wc[c0 * 2 + 3];
#pragma unroll
    for (int off = 8; off >= 1; off >>= 1) { p0 += __shfl_xor(p0, off); p1 += __shfl_xor(p1, off); }
    if (lane == 0) {
        float l0 = p0 + bc[0], l1 = p1 + bc[1];
        float m = fmaxf(l0, l1);
        float lse = m + logf(expf(l0 - m) + expf(l1 - m));
        float2 o; o.x = l0 - lse; o.y = l1 - lse;
        *(float2*)&out[(size_t)node * 2] = o;
    }
}

extern "C" void kernel_launch(void* const* d_in, const int* in_sizes, int n_in,
                              void* d_out, int out_size, void* d_ws, size_t ws_size,
                              hipStream_t stream) {
    const float* x   = (const float*)d_in[0];
    const int*   ei  = (const int*)d_in[1];     // harness converts int64 -> int32
    const float* W1  = (const float*)d_in[2];
    const float* b1  = (const float*)d_in[3];
    const float* W2  = (const float*)d_in[4];
    const float* b2  = (const float*)d_in[5];
    const float* g1  = (const float*)d_in[6];
    const float* be1 = (const float*)d_in[7];
    const float* rm1 = (const float*)d_in[8];
    const float* rv1 = (const float*)d_in[9];
    const float* g2  = (const float*)d_in[10];
    const float* be2 = (const float*)d_in[11];
    const float* rm2 = (const float*)d_in[12];
    const float* rv2 = (const float*)d_in[13];
    const float* Wc  = (const float*)d_in[14];
    const float* bc  = (const float*)d_in[15];
    float* out = (float*)d_out;

    int n = in_sizes[0] / F_IN;   // 100000
    int E = in_sizes[1] / 2;      // 1600000
    const int* srcv = ei;
    const int* dstv = ei + E;
    int NB = (n + BW - 1) / BW;   // 782

    char* ws = (char*)d_ws;
    size_t off = 0;
    auto alloc = [&](size_t bytes) -> char* {
        char* r = ws + off;
        off = (off + bytes + 511) & ~(size_t)511;
        return r;
    };
    int*      gcursor = (int*)alloc((size_t)NB * 4);
    int*      ns      = (int*)alloc((size_t)n * 4);
    int*      ne      = (int*)alloc((size_t)n * 4);
    float*    dinv    = (float*)alloc((size_t)n * 4);
    float*    A1 = (float*)alloc(HID * 4);
    float*    B1 = (float*)alloc(HID * 4);
    float*    A2 = (float*)alloc(HID2 * 4);
    float*    B2 = (float*)alloc(HID2 * 4);
    unsigned* ebuf = (unsigned*)alloc((size_t)NB * CAP * 4);  // ~8 MB; becomes csr in-place
    __half*   ht1  = (__half*)alloc((size_t)n * HID * 2);     // fp16 gather table
    float*    h1p  = (float*)alloc((size_t)n * HID * 4);
    __half*   ht2  = ht1;  // ht1 dead after agg1; reuse region

    hipMemsetAsync(gcursor, 0, (size_t)NB * 4, stream);

    int nch = (E + CH - 1) / CH;  // 196
    partition_kernel<<<nch, 1024, 0, stream>>>(srcv, dstv, E, gcursor, ebuf);
    localsort_kernel<<<NB, 256, 0, stream>>>(ebuf, gcursor, ns, ne, dinv, n);
    constprep_kernel<<<1, 64, 0, stream>>>(g1, be1, rm1, rv1, b1, g2, be2, rm2, rv2, b2, A1, B1, A2, B2);

    int ngb = (n + 63) / 64;      // 1563
    gemm1_kernel<<<ngb, 256, 0, stream>>>(x, W1, dinv, ht1, n);
    agg1_kernel<<<(n + 3) / 4, 256, 0, stream>>>(ht1, ns, ne, (const int*)ebuf, dinv, A1, B1, h1p, n);
    gemm2_kernel<<<ngb, 256, 0, stream>>>(h1p, W2, dinv, ht2, n);
    agg2_kernel<<<(n + 3) / 4, 256, 0, stream>>>(ht2, ns, ne, (const int*)ebuf, dinv, A2, B2, Wc, bc, out, n);
}

// Round 12
// 253.816 us; speedup vs baseline: 1.0721x; 1.0721x over previous
//
#include <hip/hip_runtime.h>
#include <hip/hip_fp16.h>
#include <math.h>

#define F_IN 128
#define HID 64
#define HID2 32
#define EPS_BN 1e-5f
#define BW 128          // nodes per bucket
#define NBMAX 1024      // padded bucket count (actual NB = 782)
#define CAP 2560        // max edges per bucket (mean ~2046, +11 sigma)
#define CH 8192         // edges per partition workgroup

typedef _Float16 f16x8 __attribute__((ext_vector_type(8)));
typedef float f32x4 __attribute__((ext_vector_type(4)));

// ---------------- phase A: chunk counting-sort into bucket regions (1024 thr) ----------------
__global__ __launch_bounds__(1024) void partition_kernel(const int* __restrict__ src, const int* __restrict__ dst,
                                                         int E, int* __restrict__ gcursor,
                                                         unsigned* __restrict__ ebuf) {
    __shared__ int hist[NBMAX];
    __shared__ int start[NBMAX];
    __shared__ int cur[NBMAX];
    __shared__ int gb[NBMAX];
    __shared__ int sc[1024];
    __shared__ unsigned buf[CH];  // 32 KB
    int tid = threadIdx.x;
    int e0 = blockIdx.x * CH;
    hist[tid] = 0;
    __syncthreads();
#pragma unroll
    for (int it = 0; it < CH / 1024; it++) {
        int e = e0 + tid + it * 1024;
        if (e < E) atomicAdd(&hist[dst[e] >> 7], 1);
    }
    __syncthreads();
    int v = hist[tid];
    sc[tid] = v;
    __syncthreads();
    for (int off = 1; off < 1024; off <<= 1) {
        int t = (tid >= off) ? sc[tid - off] : 0;
        __syncthreads();
        sc[tid] += t;
        __syncthreads();
    }
    int ex = sc[tid] - v;  // exclusive prefix over buckets
    start[tid] = ex;
    cur[tid] = ex;
    gb[tid] = v ? atomicAdd(&gcursor[tid], v) : 0;   // reserve run in bucket region
    __syncthreads();
#pragma unroll
    for (int it = 0; it < CH / 1024; it++) {
        int e = e0 + tid + it * 1024;
        if (e < E) {
            int d = dst[e], s = src[e];
            int p = atomicAdd(&cur[d >> 7], 1);
            buf[p] = ((unsigned)(d & (BW - 1)) << 17) | (unsigned)s;  // src < 2^17
        }
    }
    __syncthreads();
    // write phase: 256 quad-groups x 4 buckets each
    int grp = tid >> 2, sub = tid & 3;
    for (int b = grp; b < NBMAX; b += 256) {
        int len = hist[b];
        if (!len) continue;
        int st = start[b];
        unsigned* dp = ebuf + (size_t)b * CAP + gb[b];
        for (int i = sub; i < len; i += 4) dp[i] = buf[st + i];
    }
}

// ---------------- phase B: per-bucket local sort; emits ns/ne/dinv and csr (in-place) ----------------
__global__ __launch_bounds__(256) void localsort_kernel(unsigned* __restrict__ ebuf, const int* __restrict__ gcursor,
                                                        int* __restrict__ ns, int* __restrict__ ne,
                                                        float* __restrict__ dinv, int n) {
    __shared__ unsigned lbuf[CAP];
    __shared__ int lhist[BW];
    __shared__ int lcur[BW];
    __shared__ int stmp[256];
    int b = blockIdx.x;
    int tid = threadIdx.x;
    int base = b * CAP;
    int len = gcursor[b];
    int node0 = b * BW;
    int nn = min(BW, n - node0);
    if (tid < BW) lhist[tid] = 0;
    __syncthreads();
    for (int k = tid; k < len; k += 256) {
        unsigned u = ebuf[base + k];
        lbuf[k] = u;
        atomicAdd(&lhist[u >> 17], 1);
    }
    __syncthreads();
    int v = (tid < BW) ? lhist[tid] : 0;
    stmp[tid] = v;
    __syncthreads();
    for (int off = 1; off < 256; off <<= 1) {
        int t = (tid >= off) ? stmp[tid - off] : 0;
        __syncthreads();
        stmp[tid] += t;
        __syncthreads();
    }
    int ex = stmp[tid] - v;  // exclusive within bucket
    if (tid < BW) lcur[tid] = ex;
    if (tid < nn) {
        ns[node0 + tid] = base + ex;
        ne[node0 + tid] = base + ex + v;
        dinv[node0 + tid] = rsqrtf((float)(v + 1));   // +1 self-loop
    }
    __syncthreads();
    for (int k = tid; k < len; k += 256) {
        unsigned u = lbuf[k];
        int p = atomicAdd(&lcur[u >> 17], 1);
        ebuf[base + p] = u & 0x1FFFFu;               // store global src id
    }
}

// ---------------- fold BN(eval)+bias into per-column scale/shift ----------------
__global__ void constprep_kernel(const float* g1, const float* be1, const float* rm1, const float* rv1, const float* b1,
                                 const float* g2, const float* be2, const float* rm2, const float* rv2, const float* b2,
                                 float* A1, float* B1, float* A2, float* B2) {
    int t = threadIdx.x;
    if (t < HID)  { float s = g1[t] * rsqrtf(rv1[t] + EPS_BN); A1[t] = s; B1[t] = (b1[t] - rm1[t]) * s + be1[t]; }
    if (t < HID2) { float s = g2[t] * rsqrtf(rv2[t] + EPS_BN); A2[t] = s; B2[t] = (b2[t] - rm2[t]) * s + be2[t]; }
}

// ---------------- GEMM1 (MFMA fp16): ht1 = fp16( (x @ W1) * dinv[row] ) ----------------
// wave = 16-row x 64-col tile, K=128 in 4 steps of v_mfma_f32_16x16x32_f16.
// B frag: col=lane&15, k=(lane>>4)*8+e ; A frag: row=lane&15, k=(lane>>4)*8+e
// C/D:    col=lane&15, row=(lane>>4)*4+reg   [m89-verified]
__global__ __launch_bounds__(256) void gemm1_kernel(const float* __restrict__ x, const float* __restrict__ W1,
                                                    const float* __restrict__ dinv, __half* __restrict__ ht1,
                                                    int n, int nwaves_tot) {
    __shared__ float wlds[F_IN * HID];   // 32 KB, [k][col]
    int tid = threadIdx.x;
    {
        const float4* wv = (const float4*)W1;
        float4* wl = (float4*)wlds;
#pragma unroll
        for (int i = 0; i < F_IN * HID / 4 / 256; i++) wl[tid + 256 * i] = wv[tid + 256 * i];
    }
    __syncthreads();
    int lane = tid & 63;
    int l15 = lane & 15, lg = lane >> 4;
    // register-resident W fragments (fp16), built once per wave from LDS
    f16x8 bf[4][4];
#pragma unroll
    for (int ks = 0; ks < 4; ks++) {
#pragma unroll
        for (int ct = 0; ct < 4; ct++) {
            int kb = ks * 32 + lg * 8;
            int col = ct * 16 + l15;
            f16x8 b;
#pragma unroll
            for (int e = 0; e < 8; e++) b[e] = (_Float16)wlds[(kb + e) * HID + col];
            bf[ks][ct] = b;
        }
    }
    int gw = blockIdx.x * 4 + (tid >> 6);   // global wave id
    int nrt = (n + 15) >> 4;                // row-tiles of 16 (n=100000 -> 6250 exact)
    for (int rt = gw; rt < nrt; rt += nwaves_tot) {
        int arow = rt * 16 + l15;
        const float* xr = x + (size_t)min(arow, n - 1) * F_IN;
        f32x4 acc[4];
#pragma unroll
        for (int ct = 0; ct < 4; ct++) acc[ct] = (f32x4){0.f, 0.f, 0.f, 0.f};
#pragma unroll
        for (int ks = 0; ks < 4; ks++) {
            float4 xa = *(const float4*)(xr + ks * 32 + lg * 8);
            float4 xb = *(const float4*)(xr + ks * 32 + lg * 8 + 4);
            f16x8 a;
            a[0] = (_Float16)xa.x; a[1] = (_Float16)xa.y; a[2] = (_Float16)xa.z; a[3] = (_Float16)xa.w;
            a[4] = (_Float16)xb.x; a[5] = (_Float16)xb.y; a[6] = (_Float16)xb.z; a[7] = (_Float16)xb.w;
#pragma unroll
            for (int ct = 0; ct < 4; ct++)
                acc[ct] = __builtin_amdgcn_mfma_f32_16x16x32_f16(a, bf[ks][ct], acc[ct], 0, 0, 0);
        }
        int rbase = rt * 16 + lg * 4;
#pragma unroll
        for (int reg = 0; reg < 4; reg++) {
            int row = rbase + reg;
            if (row < n) {
                float d = dinv[row];
                _Float16* dp = (_Float16*)ht1 + (size_t)row * HID + l15;
#pragma unroll
                for (int ct = 0; ct < 4; ct++)
                    dp[ct * 16] = (_Float16)(acc[ct][reg] * d);
            }
        }
    }
}

// ---------------- GEMM2: ht2 = fp16( (h1p @ W2) * dinv[row] ) ----------------
#define XP2 68
__global__ __launch_bounds__(256) void gemm2_kernel(const float* __restrict__ h1p, const float* __restrict__ W2,
                                                    const float* __restrict__ dinv, __half* __restrict__ ht2,
                                                    int n) {
    __shared__ float wlds[HID * HID2];   // 8 KB, [k][col]
    __shared__ float xlds[64 * XP2];     // 17.4 KB
    int tid = threadIdx.x;
    {
        const float4* wv = (const float4*)W2;
        float4* wl = (float4*)wlds;
#pragma unroll
        for (int i = 0; i < HID * HID2 / 4 / 256; i++) wl[tid + 256 * i] = wv[tid + 256 * i];
    }
    int row0 = blockIdx.x * 64;
    {
        const float4* xv = (const float4*)(h1p + (size_t)row0 * HID);
        int lim = (n - row0) * (HID / 4);
#pragma unroll
        for (int i = 0; i < 4; i++) {
            int f = tid + 256 * i;
            float4 v = make_float4(0.f, 0.f, 0.f, 0.f);
            if (f < lim) v = xv[f];
            int r = f >> 4, kp = (f & 15) * 4;
            *(float4*)&xlds[r * XP2 + kp] = v;
        }
    }
    __syncthreads();
    int col4 = (tid & 7) * 4;
    int rowg = tid >> 3;
    float acc[2][4];
#pragma unroll
    for (int r = 0; r < 2; r++)
#pragma unroll
        for (int c = 0; c < 4; c++) acc[r][c] = 0.f;
#pragma unroll 4
    for (int k = 0; k < HID; k += 4) {
        float4 wb[4];
#pragma unroll
        for (int j = 0; j < 4; j++) wb[j] = *(const float4*)&wlds[(k + j) * HID2 + col4];
#pragma unroll
        for (int r = 0; r < 2; r++) {
            float4 xa = *(const float4*)&xlds[(rowg * 2 + r) * XP2 + k];
            acc[r][0] = fmaf(xa.x, wb[0].x, acc[r][0]); acc[r][1] = fmaf(xa.x, wb[0].y, acc[r][1]);
            acc[r][2] = fmaf(xa.x, wb[0].z, acc[r][2]); acc[r][3] = fmaf(xa.x, wb[0].w, acc[r][3]);
            acc[r][0] = fmaf(xa.y, wb[1].x, acc[r][0]); acc[r][1] = fmaf(xa.y, wb[1].y, acc[r][1]);
            acc[r][2] = fmaf(xa.y, wb[1].z, acc[r][2]); acc[r][3] = fmaf(xa.y, wb[1].w, acc[r][3]);
            acc[r][0] = fmaf(xa.z, wb[2].x, acc[r][0]); acc[r][1] = fmaf(xa.z, wb[2].y, acc[r][1]);
            acc[r][2] = fmaf(xa.z, wb[2].z, acc[r][2]); acc[r][3] = fmaf(xa.z, wb[2].w, acc[r][3]);
            acc[r][0] = fmaf(xa.w, wb[3].x, acc[r][0]); acc[r][1] = fmaf(xa.w, wb[3].y, acc[r][1]);
            acc[r][2] = fmaf(xa.w, wb[3].z, acc[r][2]); acc[r][3] = fmaf(xa.w, wb[3].w, acc[r][3]);
        }
    }
    int rbase = row0 + rowg * 2;
#pragma unroll
    for (int r = 0; r < 2; r++) {
        int row = rbase + r;
        if (row < n) {
            float d = dinv[row];
            __half2 h0, h1;
            h0.x = __float2half(acc[r][0] * d); h0.y = __float2half(acc[r][1] * d);
            h1.x = __float2half(acc[r][2] * d); h1.y = __float2half(acc[r][3] * d);
            __half2* dp = (__half2*)(ht2 + (size_t)row * HID2 + col4);
            dp[0] = h0; dp[1] = h1;
        }
    }
}

// ---------------- agg1: node-parallel, predicated 16-edge blocks (no serial remainder) ----------------
// wave = 1 node; eh = lane>>5 edge-parity, cp = lane&31 half2-column
__global__ __launch_bounds__(256) void agg1_kernel(const __half* __restrict__ ht1, const int* __restrict__ ns,
                                                   const int* __restrict__ ne, const int* __restrict__ csr,
                                                   const float* __restrict__ dinv,
                                                   const float* __restrict__ A1, const float* __restrict__ B1,
                                                   float* __restrict__ h1p, int n) {
    int node = (blockIdx.x * blockDim.x + threadIdx.x) >> 6;
    if (node >= n) return;
    int lane = threadIdx.x & 63;
    int eh = lane >> 5, cp = lane & 31;
    const __half2* htp = (const __half2*)ht1;   // [n][32] half2
    int s = ns[node], e_end = ne[node];
    float ax = 0.f, ay = 0.f;
    if (eh == 0) {  // self-loop term counted once
        float2 f = __half22float2(htp[(size_t)node * 32 + cp]);
        ax = f.x; ay = f.y;
    }
    // fully predicated: ceil(d/16) blocks of 16 slots; invalid slots clamp to csr[s]
    for (int i = s + eh; i < e_end; i += 16) {
        int idx[8];
        bool val[8];
#pragma unroll
        for (int j = 0; j < 8; j++) {
            int e = i + 2 * j;
            val[j] = e < e_end;
            idx[j] = csr[val[j] ? e : s];
        }
#pragma unroll
        for (int j = 0; j < 8; j++) {
            float2 f = __half22float2(htp[(size_t)idx[j] * 32 + cp]);
            ax += val[j] ? f.x : 0.f;
            ay += val[j] ? f.y : 0.f;
        }
    }
    ax += __shfl_xor(ax, 32);
    ay += __shfl_xor(ay, 32);
    if (eh == 0) {
        float d = dinv[node];
        int c0 = cp * 2;
        float2 o;
        o.x = fmaxf(fmaf(ax * d, A1[c0], B1[c0]), 0.f);
        o.y = fmaxf(fmaf(ay * d, A1[c0 + 1], B1[c0 + 1]), 0.f);
        *(float2*)&h1p[(size_t)node * HID + c0] = o;
    }
}

// ---------------- agg2: node-parallel, predicated 16-edge blocks + classifier + log_softmax ----------------
// eq = lane>>4 edge-quad, cp = lane&15 half2-column
__global__ __launch_bounds__(256) void agg2_kernel(const __half* __restrict__ ht2, const int* __restrict__ ns,
                                                   const int* __restrict__ ne, const int* __restrict__ csr,
                                                   const float* __restrict__ dinv,
                                                   const float* __restrict__ A2, const float* __restrict__ B2,
                                                   const float* __restrict__ Wc, const float* __restrict__ bc,
                                                   float* __restrict__ out, int n) {
    int node = (blockIdx.x * blockDim.x + threadIdx.x) >> 6;
    if (node >= n) return;
    int lane = threadIdx.x & 63;
    int eq = lane >> 4, cp = lane & 15;
    const __half2* htp = (const __half2*)ht2;   // [n][16] half2
    int s = ns[node], e_end = ne[node];
    float ax = 0.f, ay = 0.f;
    if (eq == 0) {
        float2 f = __half22float2(htp[(size_t)node * 16 + cp]);
        ax = f.x; ay = f.y;
    }
    for (int i = s + eq; i < e_end; i += 16) {
        int idx[4];
        bool val[4];
#pragma unroll
        for (int j = 0; j < 4; j++) {
            int e = i + 4 * j;
            val[j] = e < e_end;
            idx[j] = csr[val[j] ? e : s];
        }
#pragma unroll
        for (int j = 0; j < 4; j++) {
            float2 f = __half22float2(htp[(size_t)idx[j] * 16 + cp]);
            ax += val[j] ? f.x : 0.f;
            ay += val[j] ? f.y : 0.f;
        }
    }
    ax += __shfl_xor(ax, 32); ay += __shfl_xor(ay, 32);
    ax += __shfl_xor(ax, 16); ay += __shfl_xor(ay, 16);
    // all lanes hold full sums for cols 2cp, 2cp+1
    float d = dinv[node];
    int c0 = cp * 2;
    float v0 = fmaxf(fmaf(ax * d, A2[c0], B2[c0]), 0.f);
    float v1 = fmaxf(fmaf(ay * d, A2[c0 + 1], B2[c0 + 1]), 0.f);
    float p0 = v0 * Wc[c0 * 2 + 0] + v1 * Wc[c0 * 2 + 2];
    float p1 = v0 * Wc[c0 * 2 + 1] + v1 * Wc[c0 * 2 + 3];
#pragma unroll
    for (int off = 8; off >= 1; off >>= 1) { p0 += __shfl_xor(p0, off); p1 += __shfl_xor(p1, off); }
    if (lane == 0) {
        float l0 = p0 + bc[0], l1 = p1 + bc[1];
        float m = fmaxf(l0, l1);
        float lse = m + logf(expf(l0 - m) + expf(l1 - m));
        float2 o; o.x = l0 - lse; o.y = l1 - lse;
        *(float2*)&out[(size_t)node * 2] = o;
    }
}

extern "C" void kernel_launch(void* const* d_in, const int* in_sizes, int n_in,
                              void* d_out, int out_size, void* d_ws, size_t ws_size,
                              hipStream_t stream) {
    const float* x   = (const float*)d_in[0];
    const int*   ei  = (const int*)d_in[1];     // harness converts int64 -> int32
    const float* W1  = (const float*)d_in[2];
    const float* b1  = (const float*)d_in[3];
    const float* W2  = (const float*)d_in[4];
    const float* b2  = (const float*)d_in[5];
    const float* g1  = (const float*)d_in[6];
    const float* be1 = (const float*)d_in[7];
    const float* rm1 = (const float*)d_in[8];
    const float* rv1 = (const float*)d_in[9];
    const float* g2  = (const float*)d_in[10];
    const float* be2 = (const float*)d_in[11];
    const float* rm2 = (const float*)d_in[12];
    const float* rv2 = (const float*)d_in[13];
    const float* Wc  = (const float*)d_in[14];
    const float* bc  = (const float*)d_in[15];
    float* out = (float*)d_out;

    int n = in_sizes[0] / F_IN;   // 100000
    int E = in_sizes[1] / 2;      // 1600000
    const int* srcv = ei;
    const int* dstv = ei + E;
    int NB = (n + BW - 1) / BW;   // 782

    char* ws = (char*)d_ws;
    size_t off = 0;
    auto alloc = [&](size_t bytes) -> char* {
        char* r = ws + off;
        off = (off + bytes + 511) & ~(size_t)511;
        return r;
    };
    int*      gcursor = (int*)alloc((size_t)NB * 4);
    int*      ns      = (int*)alloc((size_t)n * 4);
    int*      ne      = (int*)alloc((size_t)n * 4);
    float*    dinv    = (float*)alloc((size_t)n * 4);
    float*    A1 = (float*)alloc(HID * 4);
    float*    B1 = (float*)alloc(HID * 4);
    float*    A2 = (float*)alloc(HID2 * 4);
    float*    B2 = (float*)alloc(HID2 * 4);
    unsigned* ebuf = (unsigned*)alloc((size_t)NB * CAP * 4);  // ~8 MB; becomes csr in-place
    __half*   ht1  = (__half*)alloc((size_t)n * HID * 2);     // fp16 gather table
    float*    h1p  = (float*)alloc((size_t)n * HID * 4);
    __half*   ht2  = ht1;  // ht1 dead after agg1; reuse region

    hipMemsetAsync(gcursor, 0, (size_t)NB * 4, stream);

    int nch = (E + CH - 1) / CH;  // 196
    partition_kernel<<<nch, 1024, 0, stream>>>(srcv, dstv, E, gcursor, ebuf);
    localsort_kernel<<<NB, 256, 0, stream>>>(ebuf, gcursor, ns, ne, dinv, n);
    constprep_kernel<<<1, 64, 0, stream>>>(g1, be1, rm1, rv1, b1, g2, be2, rm2, rv2, b2, A1, B1, A2, B2);

    int g1blocks = 512;           // 2048 waves, ~3 row-tiles each
    gemm1_kernel<<<g1blocks, 256, 0, stream>>>(x, W1, dinv, ht1, n, g1blocks * 4);
    agg1_kernel<<<(n + 3) / 4, 256, 0, stream>>>(ht1, ns, ne, (const int*)ebuf, dinv, A1, B1, h1p, n);
    int ngb = (n + 63) / 64;      // 1563
    gemm2_kernel<<<ngb, 256, 0, stream>>>(h1p, W2, dinv, ht2, n);
    agg2_kernel<<<(n + 3) / 4, 256, 0, stream>>>(ht2, ns, ne, (const int*)ebuf, dinv, A2, B2, Wc, bc, out, n);
}